// Round 3
// baseline (186.956 us; speedup 1.0000x reference)
//
#include <hip/hip_runtime.h>
#include <hip/hip_bf16.h>
#include <math.h>

#define N_POS 4096
#define C_DIM 528
#define NHEAD 8
#define HDIM  66
#define KNN   32
#define CQKV  1584
#define KP    544      // 528 padded to 17*32
#define NP1   1664     // 1584 padded to 13*128
#define NP2   640      // 528 padded to 5*128

typedef __attribute__((ext_vector_type(8))) short short8;
typedef __attribute__((ext_vector_type(4))) float f32x4;
typedef __hip_bfloat16 bf16;

typedef const __attribute__((address_space(1))) void* gas1;
typedef __attribute__((address_space(3))) void* las3;

// ---------------------------------------------------------------------------
// Fused f32 -> bf16 conversion with zero padding to [Npad][KP] row-major.
// ---------------------------------------------------------------------------
__global__ __launch_bounds__(256) void convpad3_kernel(
    const float* __restrict__ x, const float* __restrict__ wq,
    const float* __restrict__ wp,
    bf16* __restrict__ xb, bf16* __restrict__ wqb, bf16* __restrict__ wpb)
{
    int b = blockIdx.x;
    const float* src; bf16* dst; int Nr;
    if (b < N_POS)            { src = x;  dst = xb;  Nr = N_POS; }
    else if (b < N_POS + NP1) { b -= N_POS; src = wq; dst = wqb; Nr = CQKV; }
    else                      { b -= N_POS + NP1; src = wp; dst = wpb; Nr = C_DIM; }
    for (int c = threadIdx.x; c < KP; c += 256) {
        float v = (b < Nr && c < C_DIM) ? src[(size_t)b * C_DIM + c] : 0.0f;
        dst[(size_t)b * KP + c] = __float2bfloat16(v);
    }
}

// ---------------------------------------------------------------------------
// bf16 MFMA GEMM, m97 structure: C[m][n] = sum_k A[m][k]*B[n][k] + bias[n]
// 128x128 tile, BK=32, 4 waves (2x2), 16x16x32 MFMA, 4x4 frags/wave.
// Staging: global_load_lds dwordx4, linear LDS dest, SOURCE pre-swizzled
// col16 = (lane&3) ^ ((row>>1)&3); read side applies the same XOR ->
// fragment ds_read_b128 lands 2 lanes/bank (conflict-free, m136).
// ---------------------------------------------------------------------------
__global__ __launch_bounds__(256) void gemm_mfma_kernel(
    const bf16* __restrict__ A, const bf16* __restrict__ B,
    const float* __restrict__ bias, float* __restrict__ C,
    int Nreal, int ldc)
{
    __shared__ bf16 As[128 * 32];   // 8 KB, [row][32]
    __shared__ bf16 Bs[128 * 32];

    const int tid  = threadIdx.x;
    const int lane = tid & 63;
    const int wid  = tid >> 6;
    const int bm = blockIdx.y * 128;
    const int bn = blockIdx.x * 128;

    // staging: wave wid covers rows [32*wid, 32*wid+32) as 2 chunks of 16 rows
    const int r_lo = (wid << 5) + (lane >> 2);
    const int r_hi = r_lo + 16;
    const int csw  = ((lane & 3) ^ ((r_lo >> 1) & 3)) << 3;  // (r_hi>>1)&3 == (r_lo>>1)&3

    const bf16* Agl = A + (size_t)(bm + r_lo) * KP + csw;
    const bf16* Agh = A + (size_t)(bm + r_hi) * KP + csw;
    const bf16* Bgl = B + (size_t)(bn + r_lo) * KP + csw;
    const bf16* Bgh = B + (size_t)(bn + r_hi) * KP + csw;

    bf16* As0 = As + (wid << 5) * 32;   // wave-uniform LDS bases
    bf16* As1 = As0 + 16 * 32;
    bf16* Bs0 = Bs + (wid << 5) * 32;
    bf16* Bs1 = Bs0 + 16 * 32;

    // fragment read coords
    const int wm = (wid >> 1) * 64;
    const int wn = (wid & 1) * 64;
    const int arow = wm + (lane & 15);
    const int brow = wn + (lane & 15);
    const int seg  = lane >> 4;
    const int aoff = (seg ^ ((arow >> 1) & 3)) << 3;  // elem offset within row
    const int boff = (seg ^ ((brow >> 1) & 3)) << 3;  // ((row+16f)>>1)&3 is f-invariant

    f32x4 acc[4][4];
    #pragma unroll
    for (int i = 0; i < 4; ++i)
        #pragma unroll
        for (int j = 0; j < 4; ++j)
            acc[i][j] = (f32x4){0.f, 0.f, 0.f, 0.f};

    for (int k0 = 0; k0 < KP; k0 += 32) {
        __builtin_amdgcn_global_load_lds((gas1)(Agl + k0), (las3)As0, 16, 0, 0);
        __builtin_amdgcn_global_load_lds((gas1)(Agh + k0), (las3)As1, 16, 0, 0);
        __builtin_amdgcn_global_load_lds((gas1)(Bgl + k0), (las3)Bs0, 16, 0, 0);
        __builtin_amdgcn_global_load_lds((gas1)(Bgh + k0), (las3)Bs1, 16, 0, 0);
        __syncthreads();   // compiler drains vmcnt(0) before s_barrier

        short8 af[4], bfr[4];
        #pragma unroll
        for (int f = 0; f < 4; ++f)
            af[f] = *(const short8*)&As[(arow + f * 16) * 32 + aoff];
        #pragma unroll
        for (int f = 0; f < 4; ++f)
            bfr[f] = *(const short8*)&Bs[(brow + f * 16) * 32 + boff];

        #pragma unroll
        for (int i = 0; i < 4; ++i)
            #pragma unroll
            for (int j = 0; j < 4; ++j)
                acc[i][j] = __builtin_amdgcn_mfma_f32_16x16x32_bf16(
                    af[i], bfr[j], acc[i][j], 0, 0, 0);

        __syncthreads();   // protect LDS before next stage
    }

    // epilogue: C/D layout col=lane&15, row=(lane>>4)*4+reg  [m89/m91]
    #pragma unroll
    for (int i = 0; i < 4; ++i) {
        const int row = bm + wm + i * 16 + (lane >> 4) * 4;
        #pragma unroll
        for (int j = 0; j < 4; ++j) {
            const int col = bn + wn + j * 16 + (lane & 15);
            if (col < Nreal) {
                const float bv = bias[col];
                #pragma unroll
                for (int r = 0; r < 4; ++r)
                    C[(size_t)(row + r) * ldc + col] = acc[i][j][r] + bv;
            }
        }
    }
}

// ---------------------------------------------------------------------------
// Fused l2norm + 33-key attention. One block (256 thr) per (h, n).
// qkv: [N_POS][CQKV] f32; knn: [NHEAD][N_POS][KNN][2][HDIM] f32
// out: [N_POS][KP] bf16 (cols 528..543 zeroed by h==0 blocks)
// ---------------------------------------------------------------------------
__global__ __launch_bounds__(256) void attn_kernel(
    const float* __restrict__ qkv, const float* __restrict__ knn,
    bf16* __restrict__ out)
{
    const float scaling = 0.12309149097933272f;  // 66^-0.5

    int bid = blockIdx.x;
    int h = bid >> 12;
    int n = bid & 4095;
    int tid = threadIdx.x;

    __shared__ float s_knn[KNN * 2 * HDIM];
    __shared__ float s_q[HDIM], s_k[HDIM], s_v[HDIM];
    __shared__ float s_dot[KNN + 1];
    __shared__ float s_scale[2];

    {
        const float4* src = (const float4*)(knn + ((size_t)bid) * (KNN * 2 * HDIM));
        float4* dst = (float4*)s_knn;
        for (int i = tid; i < KNN * 2 * HDIM / 4; i += 256) dst[i] = src[i];
    }
    const float* qp = qkv + (size_t)n * CQKV + h * HDIM;
    if (tid < HDIM) {
        s_q[tid] = qp[tid];
        s_k[tid] = qp[C_DIM + tid];
        s_v[tid] = qp[2 * C_DIM + tid];
    }
    __syncthreads();

    if (tid < 64) {
        float aq = s_q[tid] * s_q[tid];
        float ak = s_k[tid] * s_k[tid];
        if (tid < 2) {
            aq += s_q[64 + tid] * s_q[64 + tid];
            ak += s_k[64 + tid] * s_k[64 + tid];
        }
        #pragma unroll
        for (int off = 32; off; off >>= 1) {
            aq += __shfl_xor(aq, off);
            ak += __shfl_xor(ak, off);
        }
        if (tid == 0) {
            s_scale[0] = 1.0f / fmaxf(sqrtf(aq), 1e-12f);
            s_scale[1] = 1.0f / fmaxf(sqrtf(ak), 1e-12f);
        }
    }
    __syncthreads();
    if (tid < HDIM) {
        s_q[tid] *= s_scale[0];
        s_k[tid] *= s_scale[1];
    }
    __syncthreads();

    {
        int g = tid >> 3, l8 = tid & 7;
        float p = 0.f;
        for (int d = l8; d < HDIM; d += 8) p += s_q[d] * s_knn[g * (2 * HDIM) + d];
        p += __shfl_xor(p, 1);
        p += __shfl_xor(p, 2);
        p += __shfl_xor(p, 4);
        if (l8 == 0) s_dot[g] = p * scaling;
    }
    if (tid < 8) {
        float p = 0.f;
        for (int d = tid; d < HDIM; d += 8) p += s_q[d] * s_k[d];
        p += __shfl_xor(p, 1);
        p += __shfl_xor(p, 2);
        p += __shfl_xor(p, 4);
        if (tid == 0) s_dot[KNN] = p * scaling;
    }
    __syncthreads();

    if (tid < 64) {
        float x = (tid < 33) ? s_dot[tid] : -3.4e38f;
        float m = x;
        #pragma unroll
        for (int off = 32; off; off >>= 1) m = fmaxf(m, __shfl_xor(m, off));
        float e = (tid < 33) ? expf(x - m) : 0.f;
        float s = e;
        #pragma unroll
        for (int off = 32; off; off >>= 1) s += __shfl_xor(s, off);
        if (tid < 33) s_dot[tid] = e / s;
    }
    __syncthreads();

    if (tid < HDIM) {
        float acc = s_dot[KNN] * s_v[tid];
        #pragma unroll 8
        for (int k = 0; k < KNN; ++k)
            acc += s_dot[k] * s_knn[k * (2 * HDIM) + HDIM + tid];
        out[(size_t)n * KP + h * HDIM + tid] = __float2bfloat16(acc);
    }
    if (h == 0 && tid < KP - C_DIM) {
        out[(size_t)n * KP + C_DIM + tid] = __float2bfloat16(0.0f);
    }
}

extern "C" void kernel_launch(void* const* d_in, const int* in_sizes, int n_in,
                              void* d_out, int out_size, void* d_ws, size_t ws_size,
                              hipStream_t stream)
{
    const float* x      = (const float*)d_in[0];
    const float* knn_kv = (const float*)d_in[1];
    const float* w_qkv  = (const float*)d_in[2];
    const float* b_qkv  = (const float*)d_in[3];
    const float* w_proj = (const float*)d_in[4];
    const float* b_proj = (const float*)d_in[5];
    float* out = (float*)d_out;

    char* ws = (char*)d_ws;
    float* qkv = (float*)ws;                                  // 4096*1584 f32 = 25,952,256 B
    bf16*  xb  = (bf16*)(ws + 25952256);                      // 4096*544*2 = 4,456,448 B
    bf16*  wqb = (bf16*)(ws + 25952256 + 4456448);            // 1664*544*2 = 1,810,432 B
    bf16*  wpb = (bf16*)(ws + 25952256 + 4456448 + 1810432);  // 640*544*2  =   696,320 B
    bf16*  ab  = (bf16*)(ws + 25952256 + 4456448 + 1810432 + 696320);  // 4096*544*2

    convpad3_kernel<<<N_POS + NP1 + NP2, 256, 0, stream>>>(x, w_qkv, w_proj, xb, wqb, wpb);

    gemm_mfma_kernel<<<dim3(NP1 / 128, N_POS / 128), 256, 0, stream>>>(
        xb, wqb, b_qkv, qkv, CQKV, CQKV);

    attn_kernel<<<dim3(NHEAD * N_POS), 256, 0, stream>>>(qkv, knn_kv, ab);

    gemm_mfma_kernel<<<dim3(NP2 / 128, N_POS / 128), 256, 0, stream>>>(
        ab, wpb, b_proj, out, C_DIM, C_DIM);
}